// Round 9
// baseline (3697.935 us; speedup 1.0000x reference)
//
#include <hip/hip_runtime.h>
#include <hip/hip_bf16.h>

typedef __bf16 bf16x8 __attribute__((ext_vector_type(8)));
typedef float f32x4 __attribute__((ext_vector_type(4)));
typedef unsigned int u32x4 __attribute__((ext_vector_type(4)));

#define BB   128
#define SS   512
#define DD   128
#define HH   1024
#define OO   64
#define IIN  257

// 8 batch groups (16 rows) x 32 blocks; block owns 32 h-cols (128 gate cols =
// 8 n-tiles of 16). 4 waves = 4 K-quarters. Entire W_hh slice (256 KB) in
// VGPRs (breg[8][8]). Broadcast halved to 8 MB/step; block-level flags cut
// poll traffic ~30x.
#define NGROUP 8
#define GBLK   32
#define MG     16
#define NTT    8      // n-tiles per block
#define KK_H   32     // 1024/32 ksteps
#define KK_X   9      // 288/32

#define XTP_TP    (KK_X*512)      // 4608 bf16 per (t,p)
#define HBUF_SLAB (KK_H*512)      // 16384 bf16 = 32 KB per (p,buf)
#define WIH_BLK   (NTT*KK_X*512)  // 36864 bf16 = 72 KB per q

// ws layout (bytes): flags 8K | hbuf 512K | hlast 512K | xtp 36M | wihp 2.25M
#define WS_HBUF  8192
#define WS_HLAST 532480
#define WS_XTP   1056768
#define WS_WIHP  38805504

// ---- device-scope (sc1) ops: bypass L1/L2, coherent at L3 (MALL). No
// buffer_wbl2/buffer_inv anywhere -> no cache-maintenance serialization.
__device__ __forceinline__ u32x4 ldg_dev16(const void* p) {
  u32x4 r;
  asm volatile("global_load_dwordx4 %0, %1, off sc1" : "=v"(r) : "v"(p));
  return r;
}
__device__ __forceinline__ void stg_dev4(void* p, unsigned int v) {
  asm volatile("global_store_dword %0, %1, off sc1" :: "v"(p), "v"(v));
}
__device__ __forceinline__ bf16x8 asbf(u32x4 v) {
  union { u32x4 u; bf16x8 h; } c; c.u = v; return c.h;
}

#define CLAIMW4(CNTSTR, A, O)                                        \
  asm volatile("s_waitcnt vmcnt(" CNTSTR ")"                         \
    : "+v"((A)[(O)]), "+v"((A)[(O)+1]), "+v"((A)[(O)+2]), "+v"((A)[(O)+3]))

// xtp A-frags (16x16x32 A: m=lane&15, k=kk*32+(lane>>4)*8+j):
// idx = ((t*8+p)*9 + kk)*512 + l*8 + j
__global__ void prepack_kernel(const float* __restrict__ x, const float* __restrict__ mask,
                               const float* __restrict__ ti, __bf16* __restrict__ xtp) {
  int idx = blockIdx.x * 256 + threadIdx.x;        // 18,874,368
  int j = idx & 7, l = (idx >> 3) & 63;
  int rest = idx >> 9;
  int kk = rest % 9;
  int rest2 = rest / 9;
  int p = rest2 & 7;
  int t = rest2 >> 3;
  int b = p * MG + (l & 15);
  int k = kk * 32 + ((l >> 4) << 3) + j;
  float v;
  if (k < 128)       v = x[(b * SS + t) * DD + k];
  else if (k < 256)  v = mask[(b * SS + t) * DD + (k - 128)];
  else if (k == 256) v = ti[b * SS + t];
  else               v = 0.f;
  xtp[idx] = (__bf16)v;
}

// W_ih B-frags per col-slice q in [0,32): [q][nt][kk][lane][8]
// nt: gate g = nt>>1, col-half hf = nt&1 -> col = g*HH + q*32 + hf*16 + (l&15)
__global__ void wih_prepack(const float* __restrict__ W_ih, __bf16* __restrict__ wihp) {
  int idx = blockIdx.x * 256 + threadIdx.x;        // 1,179,648
  int j = idx & 7, l = (idx >> 3) & 63;
  int rest = idx >> 9;
  int kk = rest % 9;
  int rest2 = rest / 9;
  int nt = rest2 & 7, q = rest2 >> 3;
  int col = (nt >> 1) * HH + q * 32 + (nt & 1) * 16 + (l & 15);
  int k = kk * 32 + ((l >> 4) << 3) + j;
  wihp[idx] = (k < IIN) ? (__bf16)W_ih[col * IIN + k] : (__bf16)0.f;
}

__device__ __forceinline__ float sigmoid_f(float v) { return 1.f / (1.f + __expf(-v)); }
__device__ __forceinline__ float tanh_f(float v)    { return 1.f - 2.f / (__expf(2.f * v) + 1.f); }

__launch_bounds__(256, 1)
__global__ void lstm_scan(const float* __restrict__ W_hh,
                          const float* __restrict__ b_ih, const float* __restrict__ b_hh,
                          const __bf16* __restrict__ xtp, const __bf16* __restrict__ wihp,
                          __bf16* __restrict__ hbuf,
                          float* __restrict__ hlast, unsigned int* __restrict__ flags) {
  // conflict-free reduce buffer: slot(w,nt,r,qh,n16) =
  //   (((w*8+nt)*4+r)*4+qh)*32 + n16*2 + (qh&1)  -> bank 2-way max
  __shared__ float red_lds[16384];   // 64 KB

  const int tid = threadIdx.x;
  const int bid = blockIdx.x;
  const int p = bid >> 5;                      // batch group [0,8)
  const int q = bid & 31;                      // col slice within group
  const int j0 = q * 32;                       // owned h-cols [j0, j0+32)

  const int w = tid >> 6, l = tid & 63;        // wave = K-quarter
  const int n16 = l & 15, qh = l >> 4;
  unsigned int* gflags = flags + p * 32;       // 32 block-flags per group

  // ---- W_hh slice fully in VGPRs: breg[nt][i], kk = w*8+i ----
  // B-frag (16x16x32): n = n16 (within tile nt), k = kk*32 + qh*8 + j
  bf16x8 breg[NTT][8];
  #pragma unroll
  for (int ntI = 0; ntI < NTT; ++ntI) {
    const float* wrow = W_hh + (size_t)((ntI >> 1) * HH + j0 + (ntI & 1) * 16 + n16) * HH;
    #pragma unroll
    for (int i = 0; i < 8; ++i) {
      const float* src = wrow + (w * 8 + i) * 32 + qh * 8;
      bf16x8 bv;
      #pragma unroll
      for (int jj = 0; jj < 8; ++jj) bv[jj] = (__bf16)src[jj];
      breg[ntI][i] = bv;
    }
  }

  // gate-phase cell ownership: thread owns row grow = qh*4 + w,
  // cols c_s = j0 + s*16 + n16 for s in {0,1}
  const int grow = qh * 4 + w;
  float bias_r[4][2];
  #pragma unroll
  for (int g = 0; g < 4; ++g)
    #pragma unroll
    for (int s = 0; s < 2; ++s)
      bias_r[g][s] = b_ih[g * HH + j0 + s * 16 + n16] + b_hh[g * HH + j0 + s * 16 + n16];
  float creg[2] = {0.f, 0.f};

  // x-part K split over waves: kk in [xs, xe)
  const int xs = (w == 0) ? 0 : (2 * w + 1);
  const int xe = xs + ((w == 0) ? 3 : 2);

  for (int t = 0; t < SS; ++t) {
    const int rb = t & 1, wb = rb ^ 1;
    f32x4 acc[NTT];
    #pragma unroll
    for (int ntI = 0; ntI < NTT; ++ntI) acc[ntI] = (f32x4){0.f, 0.f, 0.f, 0.f};

    // x-part (this wave's K-slice), pre-poll; A from xtp, B from wihp (L2-hot)
    for (int kk = xs; kk < xe; ++kk) {
      const __bf16* xb = xtp + ((size_t)(t * 8 + p) * KK_X + kk) * 512 + l * 8;
      bf16x8 a = *(const bf16x8*)xb;
      #pragma unroll
      for (int ntI = 0; ntI < NTT; ++ntI) {
        bf16x8 b = *(const bf16x8*)(wihp + ((size_t)(q * NTT + ntI) * KK_X + kk) * 512 + l * 8);
        acc[ntI] = __builtin_amdgcn_mfma_f32_16x16x32_bf16(a, b, acc[ntI], 0, 0, 0);
      }
    }

    // ---- barrier wait: all 32 group blocks published h_t (block-level flags,
    // 128 B per poll iteration, no sleep) ----
    if (t > 0) {
      if (tid < 64) {
        const unsigned int tgt = (unsigned int)t;
        for (;;) {
          unsigned int fa;
          asm volatile("global_load_dword %0, %1, off sc1\n\t"
                       "s_waitcnt vmcnt(0)"
                       : "=v"(fa) : "v"(gflags + (tid & 31)));
          if (!__ballot(fa < tgt)) break;
        }
      }
      __syncthreads();
    }

    // h-part: this wave's K-quarter (8 ksteps). A via sc1 from L3, B from VGPRs.
    {
      const __bf16* hbL = hbuf + (p * 2 + rb) * HBUF_SLAB + (w * 8) * 512 + l * 8;
      u32x4 A[8];
      #pragma unroll
      for (int i = 0; i < 8; ++i) A[i] = ldg_dev16(hbL + i * 512);

      CLAIMW4("4", A, 0);
      #pragma unroll
      for (int i = 0; i < 4; ++i)
        #pragma unroll
        for (int ntI = 0; ntI < NTT; ++ntI)
          acc[ntI] = __builtin_amdgcn_mfma_f32_16x16x32_bf16(asbf(A[i]), breg[ntI][i], acc[ntI], 0, 0, 0);
      CLAIMW4("0", A, 4);
      #pragma unroll
      for (int i = 4; i < 8; ++i)
        #pragma unroll
        for (int ntI = 0; ntI < NTT; ++ntI)
          acc[ntI] = __builtin_amdgcn_mfma_f32_16x16x32_bf16(asbf(A[i]), breg[ntI][i], acc[ntI], 0, 0, 0);
    }

    // ---- deposit K-partials (conflict-free banking) ----
    #pragma unroll
    for (int ntI = 0; ntI < NTT; ++ntI)
      #pragma unroll
      for (int r = 0; r < 4; ++r)
        red_lds[(((w * 8 + ntI) * 4 + r) * 4 + qh) * 32 + n16 * 2 + (qh & 1)] = acc[ntI][r];
    __syncthreads();

    // ---- gate phase: 2 cells/thread (grow, j0+s*16+n16); own partial in reg ----
    {
      __bf16* hw = hbuf + (p * 2 + wb) * HBUF_SLAB;
      float h2[2];
      #pragma unroll
      for (int s = 0; s < 2; ++s) {
        float gv[4];
        #pragma unroll
        for (int g = 0; g < 4; ++g) {
          int nt = g * 2 + s;
          float own = (w == 0) ? acc[nt][0] : (w == 1) ? acc[nt][1]
                    : (w == 2) ? acc[nt][2] : acc[nt][3];
          float sum = own + bias_r[g][s];
          #pragma unroll
          for (int wo = 0; wo < 4; ++wo)
            if (wo != w)
              sum += red_lds[(((wo * 8 + nt) * 4 + w) * 4 + qh) * 32 + n16 * 2 + (qh & 1)];
          gv[g] = sum;
        }
        float i_ = sigmoid_f(gv[0]);
        float f_ = sigmoid_f(gv[1]);
        float g_ = tanh_f(gv[2]);
        float o_ = sigmoid_f(gv[3]);
        float c  = f_ * creg[s] + i_ * g_;
        creg[s] = c;
        h2[s] = o_ * tanh_f(c);
      }
      // pack adjacent-col pairs via shfl; even n16 lanes store one dword per s
      #pragma unroll
      for (int s = 0; s < 2; ++s) {
        union { __bf16 b; unsigned short u; } cv; cv.b = (__bf16)h2[s];
        unsigned int hu = (unsigned int)cv.u;
        unsigned int partner = __shfl_xor(hu, 1);
        if ((n16 & 1) == 0) {
          unsigned int dw = hu | (partner << 16);
          int k = j0 + s * 16 + n16;
          int kk = k >> 5, q2 = (k >> 3) & 3, jj = k & 7;
          stg_dev4(hw + kk * 512 + (q2 * 16 + grow) * 8 + jj, dw);
        }
        if (t == SS - 1)
          hlast[(p * MG + grow) * HH + j0 + s * 16 + n16] = h2[s];
      }
    }

    // ---- signal: all waves drain h stores, then one block-level flag ----
    asm volatile("s_waitcnt vmcnt(0)" ::: "memory");
    __syncthreads();
    if (t < SS - 1 && tid == 0) {
      stg_dev4(gflags + q, (unsigned int)(t + 1));
    }
  }
}

__global__ void fc_kernel(const float* __restrict__ hlast, const float* __restrict__ W_fc,
                          const float* __restrict__ b_fc, float* __restrict__ out) {
  int b = blockIdx.x;            // 128
  int t = threadIdx.x;           // 256
  int o = t >> 2, part = t & 3;
  const float* hr = hlast + b * HH;
  const float* wr = W_fc + o * HH;
  float s = 0.f;
  #pragma unroll 4
  for (int k0 = part * 4; k0 < HH; k0 += 16) {
    float4 hv = *(const float4*)(hr + k0);
    float4 wv = *(const float4*)(wr + k0);
    s += hv.x * wv.x + hv.y * wv.y + hv.z * wv.z + hv.w * wv.w;
  }
  s += __shfl_xor(s, 1);
  s += __shfl_xor(s, 2);
  if (part == 0) out[b * OO + o] = s + b_fc[o];
}

extern "C" void kernel_launch(void* const* d_in, const int* in_sizes, int n_in,
                              void* d_out, int out_size, void* d_ws, size_t ws_size,
                              hipStream_t stream) {
  const float* x    = (const float*)d_in[0];
  const float* mask = (const float*)d_in[1];
  const float* ti   = (const float*)d_in[2];
  const float* W_ih = (const float*)d_in[3];
  const float* W_hh = (const float*)d_in[4];
  const float* b_ih = (const float*)d_in[5];
  const float* b_hh = (const float*)d_in[6];
  const float* W_fc = (const float*)d_in[7];
  const float* b_fc = (const float*)d_in[8];
  float* out = (float*)d_out;

  char* ws = (char*)d_ws;
  unsigned int* flags = (unsigned int*)ws;
  __bf16* hbuf  = (__bf16*)(ws + WS_HBUF);
  float*  hlast = (float*)(ws + WS_HLAST);
  __bf16* xtp   = (__bf16*)(ws + WS_XTP);
  __bf16* wihp  = (__bf16*)(ws + WS_WIHP);

  // zero flags + h double-buffers (ws poisoned 0xAA before each launch)
  hipMemsetAsync(ws, 0, WS_HLAST, stream);

  prepack_kernel<<<(SS * NGROUP * XTP_TP) / 256, 256, 0, stream>>>(x, mask, ti, xtp);
  wih_prepack<<<(GBLK * WIH_BLK) / 256, 256, 0, stream>>>(W_ih, wihp);
  lstm_scan<<<NGROUP * GBLK, 256, 0, stream>>>(W_hh, b_ih, b_hh, xtp, wihp, hbuf, hlast, flags);
  fc_kernel<<<BB, 256, 0, stream>>>(hlast, W_fc, b_fc, out);
}